// Round 11
// baseline (1501.080 us; speedup 1.0000x reference)
//
#include <hip/hip_runtime.h>

// SplineConv (degree-1 B-spline, DIM=2, K=5, open), N=100000, E=1600000, 32->32.
// R11: abandon the MFMA/bucket path (R8/R9/R10 all show an ~1.3e-2 launch-
//      order-sensitive error that no quantization model explains; A-precision
//      provably not the cause since hi+lo A scored the same as bf16 A).
//      Instead use the reference's own factorization, pure fp32:
//        phase 1: h[n,k,i] = sum_edges basis*x  (LDS scatter, NO weights/edge)
//        phase 2: out[n,o] = sum_ki h[n][ki] * W[ki*32+o]  (coalesced fp32 W)
//      Fused per 8-row block over R7's proven row-CSR. h pitch 801 -> phase-1
//      banks (n+ch)&31 conflict-free, phase-2 broadcast reads. No bf16
//      anywhere -> absmax ~1e-5, deterministic. Bodies straight-line, no
//      cross-edge register state (the R4/R5/R6 spill lesson).

#define NN   100000
#define EE   1600000

// ws layout (int32 units): counts | offsets | cursor | blksum | sorted
#define WS_COUNTS  0
#define WS_OFFSETS 100000
#define WS_CURSOR  200000
#define WS_BLKSUM  300000
#define WS_SORTED  300128
#define SCAN_NBLK  98               // ceil(100000/1024)

__global__ void hist_kernel(const int* __restrict__ eidx, int* __restrict__ counts) {
    for (int e = blockIdx.x * blockDim.x + threadIdx.x; e < EE; e += gridDim.x * blockDim.x)
        atomicAdd(&counts[eidx[e]], 1);
}

__global__ __launch_bounds__(1024)
void scan1_kernel(const int* __restrict__ counts, int* __restrict__ offsets,
                  int* __restrict__ blksum) {
    __shared__ int buf[2][1024];
    int tid = threadIdx.x;
    int gid = blockIdx.x * 1024 + tid;
    int v = (gid < NN) ? counts[gid] : 0;
    buf[0][tid] = v;
    __syncthreads();
    int s = 0;
    for (int off = 1; off < 1024; off <<= 1) {
        int t = buf[s][tid];
        if (tid >= off) t += buf[s][tid - off];
        buf[1 - s][tid] = t;
        s ^= 1;
        __syncthreads();
    }
    if (gid < NN) offsets[gid] = buf[s][tid] - v;      // exclusive
    if (tid == 1023) blksum[blockIdx.x] = buf[s][tid]; // block total
}

__global__ void scan2_kernel(int* __restrict__ blksum) {
    if (blockIdx.x == 0 && threadIdx.x == 0) {
        int acc = 0;
        for (int i = 0; i < SCAN_NBLK; ++i) { int v = blksum[i]; blksum[i] = acc; acc += v; }
    }
}

__global__ __launch_bounds__(1024)
void scan3_kernel(int* __restrict__ offsets, const int* __restrict__ blksum,
                  int* __restrict__ cursor) {
    int gid = blockIdx.x * 1024 + threadIdx.x;
    if (gid < NN) {
        int o = offsets[gid] + blksum[blockIdx.x];
        offsets[gid] = o;
        cursor[gid] = o;
    }
}

__global__ void scatter_kernel(const int* __restrict__ eidx, int* __restrict__ cursor,
                               int* __restrict__ sorted) {
    for (int e = blockIdx.x * blockDim.x + threadIdx.x; e < EE; e += gridDim.x * blockDim.x) {
        int pos = atomicAdd(&cursor[eidx[e]], 1);
        sorted[pos] = e;
    }
}

__global__ __launch_bounds__(256, 4)
void fused_kernel(const float* __restrict__ x,
                  const int* __restrict__ eidx,
                  const float* __restrict__ pseudo,
                  const float* __restrict__ weight,   // [25][32][32] fp32; linear ki*32+o
                  const float* __restrict__ rootw,    // [32][32]
                  const float* __restrict__ bias,     // [32]
                  const int* __restrict__ offsets,
                  const int* __restrict__ cursor,     // row end offsets
                  const int* __restrict__ counts,     // row degrees
                  const int* __restrict__ sorted,
                  float* __restrict__ out)
{
    __shared__ float h[8 * 801];   // 25632 B; pitch 801 -> bank (n+ki)&31

    for (int i = threadIdx.x; i < 8 * 801; i += 256) h[i] = 0.0f;
    __syncthreads();

    const int row0  = blockIdx.x * 8;
    const int rlast = min(row0 + 8, NN) - 1;
    const int start = offsets[row0];
    const int end   = cursor[rlast];
    const int hw = threadIdx.x >> 5;   // half-wave id 0..7 (one edge each)
    const int ch = threadIdx.x & 31;   // channel lane

    // Phase 1: scatter basis-weighted x into the h tile. Straight-line body,
    // results consumed immediately (ds atomic) -> no spillable state.
    for (int i = start + hw; i < end; i += 8) {
        int e   = sorted[i];
        int row = eidx[e];
        int col = eidx[EE + e];
        float2 ps = ((const float2*)pseudo)[e];
        float p0 = ps.x * 4.0f, p1 = ps.y * 4.0f;
        float l0f = floorf(p0), l1f = floorf(p1);
        float f0 = p0 - l0f, f1 = p1 - l1f;
        int l0 = (int)l0f, l1 = (int)l1f;
        int i0a = min(max(l0, 0), 4),     i0b = min(max(l0 + 1, 0), 4);
        int i1a = min(max(l1, 0), 4),     i1b = min(max(l1 + 1, 0), 4);
        float xv = x[(size_t)col * 32 + ch];
        float* hr = &h[(row - row0) * 801];
        atomicAdd(&hr[(i0a + 5 * i1a) * 32 + ch], (1.0f - f0) * (1.0f - f1) * xv);
        atomicAdd(&hr[(i0b + 5 * i1a) * 32 + ch], f0 * (1.0f - f1) * xv);
        atomicAdd(&hr[(i0a + 5 * i1b) * 32 + ch], (1.0f - f0) * f1 * xv);
        atomicAdd(&hr[(i0b + 5 * i1b) * 32 + ch], f0 * f1 * xv);
    }
    __syncthreads();

    // Phase 2: out[n,o] = (1/deg) sum_ki h[n][ki]*W[ki][o] + x[n]@root + bias.
    // h-read: 32 o-lanes broadcast one address; W-read: 128B coalesced line.
    const int n   = hw;
    const int row = row0 + n;
    if (row < NN) {
        const float* hr = &h[n * 801];
        float acc = 0.0f;
        #pragma unroll 8
        for (int ki = 0; ki < 800; ++ki)
            acc = fmaf(hr[ki], weight[ki * 32 + ch], acc);
        float dg = fmaxf((float)counts[row], 1.0f);
        float v = 0.0f;
        const float* xr = x + (size_t)row * 32;
        #pragma unroll
        for (int i = 0; i < 32; ++i)
            v = fmaf(xr[i], rootw[i * 32 + ch], v);
        out[(size_t)row * 32 + ch] = acc / dg + v + bias[ch];
    }
}

extern "C" void kernel_launch(void* const* d_in, const int* in_sizes, int n_in,
                              void* d_out, int out_size, void* d_ws, size_t ws_size,
                              hipStream_t stream) {
    const float* x      = (const float*)d_in[0];
    const int*   eidx   = (const int*)d_in[1];
    const float* pseudo = (const float*)d_in[2];
    const float* weight = (const float*)d_in[3];
    const float* rootw  = (const float*)d_in[4];
    const float* bias   = (const float*)d_in[5];
    float* out = (float*)d_out;

    int* ws      = (int*)d_ws;
    int* counts  = ws + WS_COUNTS;
    int* offsets = ws + WS_OFFSETS;
    int* cursor  = ws + WS_CURSOR;
    int* blksum  = ws + WS_BLKSUM;
    int* sorted  = ws + WS_SORTED;

    hipMemsetAsync(counts, 0, (size_t)NN * sizeof(int), stream);

    hist_kernel   <<<2048, 256, 0, stream>>>(eidx, counts);
    scan1_kernel  <<<SCAN_NBLK, 1024, 0, stream>>>(counts, offsets, blksum);
    scan2_kernel  <<<1, 64, 0, stream>>>(blksum);
    scan3_kernel  <<<SCAN_NBLK, 1024, 0, stream>>>(offsets, blksum, cursor);
    scatter_kernel<<<2048, 256, 0, stream>>>(eidx, cursor, sorted);

    fused_kernel<<<NN / 8, 256, 0, stream>>>(
        x, eidx, pseudo, weight, rootw, bias, offsets, cursor, counts, sorted, out);
}